// Round 4
// baseline (1238.989 us; speedup 1.0000x reference)
//
#include <hip/hip_runtime.h>

#define P_N   20000
#define K_N   16
#define C_N   100
#define NCOL  20100   // P + C
#define NC4   5025    // NCOL / 4 (exact)
#define NUM_ITER 2
#define ROWS  16      // rows per matvec block (divides P_N)

typedef float f4 __attribute__((ext_vector_type(4)));

// ---------------- L-apply: out = sum_k x[nbr]*w + diag*x ----------------
__global__ __launch_bounds__(256) void mul_L_kernel(const float* __restrict__ x,
    const int* __restrict__ nbrs, const float* __restrict__ wgts,
    const float* __restrict__ diag, float* __restrict__ out) {
  int p = blockIdx.x * blockDim.x + threadIdx.x;
  if (p >= P_N) return;
  float xx = x[3*p], xy = x[3*p+1], xz = x[3*p+2];
  float ax = 0.f, ay = 0.f, az = 0.f;
  #pragma unroll
  for (int k = 0; k < K_N; ++k) {
    int nb = nbrs[p*K_N + k];
    float w = wgts[p*K_N + k];
    ax += x[3*nb]   * w;
    ay += x[3*nb+1] * w;
    az += x[3*nb+2] * w;
  }
  float d = diag[p];
  out[3*p]   = ax + d*xx;
  out[3*p+1] = ay + d*xy;
  out[3*p+2] = az + d*xz;
}

// ------- fused: rhsT[:, j] = (L @ x)[j] for j<P, crhs for j>=P (3 planes) -------
__global__ __launch_bounds__(256) void mulL_pack_kernel(const float* __restrict__ x,
    const int* __restrict__ nbrs, const float* __restrict__ wgts,
    const float* __restrict__ diag, const float* __restrict__ crhs,
    float* __restrict__ rhsT) {
  int j = blockIdx.x * blockDim.x + threadIdx.x;
  if (j >= NCOL) return;
  float v0, v1, v2;
  if (j < P_N) {
    float xx = x[3*j], xy = x[3*j+1], xz = x[3*j+2];
    float ax = 0.f, ay = 0.f, az = 0.f;
    #pragma unroll
    for (int k = 0; k < K_N; ++k) {
      int nb = nbrs[j*K_N + k];
      float w = wgts[j*K_N + k];
      ax += x[3*nb]   * w;
      ay += x[3*nb+1] * w;
      az += x[3*nb+2] * w;
    }
    float d = diag[j];
    v0 = ax + d*xx; v1 = ay + d*xy; v2 = az + d*xz;
  } else {
    int q = j - P_N;
    v0 = crhs[3*q]; v1 = crhs[3*q+1]; v2 = crhs[3*q+2];
  }
  rhsT[j] = v0; rhsT[NCOL + j] = v1; rhsT[2*NCOL + j] = v2;
}

// ------- GEMV, 16 rows per block, 3 rhs columns: out[row,:] = iA[row,:] @ rhsT -------
__global__ __launch_bounds__(256) void matvec_kernel(const float* __restrict__ A,
    const float* __restrict__ rhsT, float* __restrict__ out) {
  int row0 = blockIdx.x * ROWS;
  const f4* __restrict__ Ablk = reinterpret_cast<const f4*>(A) + (size_t)row0 * NC4;
  const f4* __restrict__ r0 = reinterpret_cast<const f4*>(rhsT);
  const f4* __restrict__ r1 = reinterpret_cast<const f4*>(rhsT + NCOL);
  const f4* __restrict__ r2 = reinterpret_cast<const f4*>(rhsT + 2*NCOL);
  float acc[ROWS][3];
  #pragma unroll
  for (int r = 0; r < ROWS; ++r) { acc[r][0] = 0.f; acc[r][1] = 0.f; acc[r][2] = 0.f; }
  for (int j = threadIdx.x; j < NC4; j += 256) {
    f4 b0 = r0[j];
    f4 b1 = r1[j];
    f4 b2 = r2[j];
    #pragma unroll
    for (int r = 0; r < ROWS; ++r) {
      f4 a = __builtin_nontemporal_load(Ablk + (size_t)r * NC4 + j);
      acc[r][0] = fmaf(a.x,b0.x, fmaf(a.y,b0.y, fmaf(a.z,b0.z, fmaf(a.w,b0.w, acc[r][0]))));
      acc[r][1] = fmaf(a.x,b1.x, fmaf(a.y,b1.y, fmaf(a.z,b1.z, fmaf(a.w,b1.w, acc[r][1]))));
      acc[r][2] = fmaf(a.x,b2.x, fmaf(a.y,b2.y, fmaf(a.z,b2.z, fmaf(a.w,b2.w, acc[r][2]))));
    }
  }
  // wave-level reduce
  #pragma unroll
  for (int off = 32; off > 0; off >>= 1) {
    #pragma unroll
    for (int r = 0; r < ROWS; ++r) {
      acc[r][0] += __shfl_down(acc[r][0], off);
      acc[r][1] += __shfl_down(acc[r][1], off);
      acc[r][2] += __shfl_down(acc[r][2], off);
    }
  }
  __shared__ float red[4][ROWS][3];
  int wid = threadIdx.x >> 6, lane = threadIdx.x & 63;
  if (lane == 0) {
    #pragma unroll
    for (int r = 0; r < ROWS; ++r) {
      red[wid][r][0] = acc[r][0];
      red[wid][r][1] = acc[r][1];
      red[wid][r][2] = acc[r][2];
    }
  }
  __syncthreads();
  if (threadIdx.x < ROWS*3) {
    int r = threadIdx.x / 3, c = threadIdx.x % 3;
    float s = red[0][r][c] + red[1][r][c] + red[2][r][c] + red[3][r][c];
    out[3*(row0+r)+c] = s;
  }
}

// ---------------- Jacobi rotation on symmetric S (pair PP<QQ, other RR), V accumulates ----------------
template<int PP, int QQ, int RR>
__device__ __forceinline__ void jacobi_rot(float S[3][3], float V[3][3]) {
  float apq = S[PP][QQ];
  if (fabsf(apq) < 1e-30f) return;
  float app = S[PP][PP], aqq = S[QQ][QQ];
  float tau = (aqq - app) / (2.0f * apq);
  float t = (tau >= 0.f ? 1.f : -1.f) / (fabsf(tau) + sqrtf(1.f + tau*tau));
  float c = 1.0f / sqrtf(1.f + t*t);
  float s = t * c;
  float arp = S[PP][RR], arq = S[QQ][RR];
  float npp = c*c*app - 2.f*s*c*apq + s*s*aqq;
  float nqq = s*s*app + 2.f*s*c*apq + c*c*aqq;
  S[PP][PP] = npp; S[QQ][QQ] = nqq;
  S[PP][QQ] = 0.f; S[QQ][PP] = 0.f;
  float narp = c*arp - s*arq;
  float narq = s*arp + c*arq;
  S[PP][RR] = narp; S[RR][PP] = narp;
  S[QQ][RR] = narq; S[RR][QQ] = narq;
  #pragma unroll
  for (int i = 0; i < 3; ++i) {
    float vp = V[i][PP], vq = V[i][QQ];
    V[i][PP] = c*vp - s*vq;
    V[i][QQ] = s*vp + c*vq;
  }
}

// ---------------- per-vertex Kabsch rotation from cov = N^T O ----------------
__global__ __launch_bounds__(256) void compute_R_kernel(const float* __restrict__ oldp,
    const float* __restrict__ newp, const int* __restrict__ nbrs,
    const float* __restrict__ wgts, float* __restrict__ Rout) {
  int p = blockIdx.x * blockDim.x + threadIdx.x;
  if (p >= P_N) return;
  float ox = oldp[3*p], oy = oldp[3*p+1], oz = oldp[3*p+2];
  float nx = newp[3*p], ny = newp[3*p+1], nz = newp[3*p+2];
  float c00=0,c01=0,c02=0,c10=0,c11=0,c12=0,c20=0,c21=0,c22=0;
  #pragma unroll
  for (int k = 0; k < K_N; ++k) {
    int nb = nbrs[p*K_N + k];
    float w = wgts[p*K_N + k];
    float Ox = (ox - oldp[3*nb])   * w;
    float Oy = (oy - oldp[3*nb+1]) * w;
    float Oz = (oz - oldp[3*nb+2]) * w;
    float Nx = (nx - newp[3*nb])   * w;
    float Ny = (ny - newp[3*nb+1]) * w;
    float Nz = (nz - newp[3*nb+2]) * w;
    c00 += Nx*Ox; c01 += Nx*Oy; c02 += Nx*Oz;
    c10 += Ny*Ox; c11 += Ny*Oy; c12 += Ny*Oz;
    c20 += Nz*Ox; c21 += Nz*Oy; c22 += Nz*Oz;
  }
  float S[3][3];
  S[0][0] = c00*c00 + c10*c10 + c20*c20;
  S[1][1] = c01*c01 + c11*c11 + c21*c21;
  S[2][2] = c02*c02 + c12*c12 + c22*c22;
  S[0][1] = c00*c01 + c10*c11 + c20*c21; S[1][0] = S[0][1];
  S[0][2] = c00*c02 + c10*c12 + c20*c22; S[2][0] = S[0][2];
  S[1][2] = c01*c02 + c11*c12 + c21*c22; S[2][1] = S[1][2];
  float V[3][3] = {{1.f,0.f,0.f},{0.f,1.f,0.f},{0.f,0.f,1.f}};
  #pragma unroll
  for (int sweep = 0; sweep < 8; ++sweep) {
    jacobi_rot<0,1,2>(S, V);
    jacobi_rot<0,2,1>(S, V);
    jacobi_rot<1,2,0>(S, V);
  }
  float e0 = S[0][0], e1 = S[1][1], e2 = S[2][2];
  float v0x=V[0][0], v0y=V[1][0], v0z=V[2][0];
  float v1x=V[0][1], v1y=V[1][1], v1z=V[2][1];
  float v2x=V[0][2], v2y=V[1][2], v2z=V[2][2];
  float te, tx, ty, tz;
  if (e1 > e0) { te=e0;e0=e1;e1=te; tx=v0x;ty=v0y;tz=v0z; v0x=v1x;v0y=v1y;v0z=v1z; v1x=tx;v1y=ty;v1z=tz; }
  if (e2 > e0) { te=e0;e0=e2;e2=te; tx=v0x;ty=v0y;tz=v0z; v0x=v2x;v0y=v2y;v0z=v2z; v2x=tx;v2y=ty;v2z=tz; }
  if (e2 > e1) { te=e1;e1=e2;e2=te; tx=v1x;ty=v1y;tz=v1z; v1x=v2x;v1y=v2y;v1z=v2z; v2x=tx;v2y=ty;v2z=tz; }
  float u0x = c00*v0x + c01*v0y + c02*v0z;
  float u0y = c10*v0x + c11*v0y + c12*v0z;
  float u0z = c20*v0x + c21*v0y + c22*v0z;
  float n0 = sqrtf(u0x*u0x + u0y*u0y + u0z*u0z);
  float R00,R01,R02,R10,R11,R12,R20,R21,R22;
  if (n0 < 1e-25f) {
    R00=1.f;R01=0.f;R02=0.f;R10=0.f;R11=1.f;R12=0.f;R20=0.f;R21=0.f;R22=1.f;
  } else {
    float in0 = 1.f/n0; u0x*=in0; u0y*=in0; u0z*=in0;
    float u1x = c00*v1x + c01*v1y + c02*v1z;
    float u1y = c10*v1x + c11*v1y + c12*v1z;
    float u1z = c20*v1x + c21*v1y + c22*v1z;
    float d01 = u1x*u0x + u1y*u0y + u1z*u0z;
    u1x -= d01*u0x; u1y -= d01*u0y; u1z -= d01*u0z;
    float n1 = sqrtf(u1x*u1x + u1y*u1y + u1z*u1z);
    if (n1 > 1e-6f * n0) {
      float in1 = 1.f/n1; u1x*=in1; u1y*=in1; u1z*=in1;
    } else {
      if (fabsf(u0x) < 0.7f) {
        float nn = 1.f/sqrtf(u0z*u0z + u0y*u0y + 1e-30f);
        u1x = 0.f; u1y = u0z*nn; u1z = -u0y*nn;
      } else {
        float nn = 1.f/sqrtf(u0z*u0z + u0x*u0x + 1e-30f);
        u1x = -u0z*nn; u1y = 0.f; u1z = u0x*nn;
      }
    }
    float u2x = u0y*u1z - u0z*u1y;
    float u2y = u0z*u1x - u0x*u1z;
    float u2z = u0x*u1y - u0y*u1x;
    float detV = v0x*(v1y*v2z - v1z*v2y) - v0y*(v1x*v2z - v1z*v2x) + v0z*(v1x*v2y - v1y*v2x);
    float sg = (detV >= 0.f) ? 1.f : -1.f;
    R00 = u0x*v0x + u1x*v1x + sg*u2x*v2x;
    R01 = u0x*v0y + u1x*v1y + sg*u2x*v2y;
    R02 = u0x*v0z + u1x*v1z + sg*u2x*v2z;
    R10 = u0y*v0x + u1y*v1x + sg*u2y*v2x;
    R11 = u0y*v0y + u1y*v1y + sg*u2y*v2y;
    R12 = u0y*v0z + u1y*v1z + sg*u2y*v2z;
    R20 = u0z*v0x + u1z*v1x + sg*u2z*v2x;
    R21 = u0z*v0y + u1z*v1y + sg*u2z*v2y;
    R22 = u0z*v0z + u1z*v1z + sg*u2z*v2z;
  }
  float* Rp = Rout + (size_t)p * 9;
  Rp[0]=R00; Rp[1]=R01; Rp[2]=R02;
  Rp[3]=R10; Rp[4]=R11; Rp[5]=R12;
  Rp[6]=R20; Rp[7]=R21; Rp[8]=R22;
}

// ---------------- d_new = sum_k 0.5*w_k*(R[nbr]+R[p]) @ O_k ----------------
__global__ __launch_bounds__(256) void dnew_kernel(const float* __restrict__ oldp,
    const int* __restrict__ nbrs, const float* __restrict__ wgts,
    const float* __restrict__ Rbuf, float* __restrict__ dnew) {
  int p = blockIdx.x * blockDim.x + threadIdx.x;
  if (p >= P_N) return;
  float ox = oldp[3*p], oy = oldp[3*p+1], oz = oldp[3*p+2];
  const float* Rp = Rbuf + (size_t)p * 9;
  float p00=Rp[0],p01=Rp[1],p02=Rp[2],p10=Rp[3],p11=Rp[4],p12=Rp[5],p20=Rp[6],p21=Rp[7],p22=Rp[8];
  float ax = 0.f, ay = 0.f, az = 0.f;
  #pragma unroll
  for (int k = 0; k < K_N; ++k) {
    int nb = nbrs[p*K_N + k];
    float w = wgts[p*K_N + k];
    float Ox = (ox - oldp[3*nb])   * w;
    float Oy = (oy - oldp[3*nb+1]) * w;
    float Oz = (oz - oldp[3*nb+2]) * w;
    const float* Rn = Rbuf + (size_t)nb * 9;
    float r00=Rn[0]+p00, r01=Rn[1]+p01, r02=Rn[2]+p02;
    float r10=Rn[3]+p10, r11=Rn[4]+p11, r12=Rn[5]+p12;
    float r20=Rn[6]+p20, r21=Rn[7]+p21, r22=Rn[8]+p22;
    float hw = 0.5f * w;
    ax += hw * (r00*Ox + r01*Oy + r02*Oz);
    ay += hw * (r10*Ox + r11*Oy + r12*Oz);
    az += hw * (r20*Ox + r21*Oy + r22*Oz);
  }
  dnew[3*p]   = ax;
  dnew[3*p+1] = ay;
  dnew[3*p+2] = az;
}

extern "C" void kernel_launch(void* const* d_in, const int* in_sizes, int n_in,
                              void* d_out, int out_size, void* d_ws, size_t ws_size,
                              hipStream_t stream) {
  const float* pnts = (const float*)d_in[0];
  const int*   nbrs = (const int*)d_in[1];
  const float* wgts = (const float*)d_in[2];
  const float* diag = (const float*)d_in[3];
  const float* crhs = (const float*)d_in[4];
  const float* iA   = (const float*)d_in[5];
  float* out = (float*)d_out;

  float* ws   = (float*)d_ws;
  float* rhsT = ws;                 // 3 * 20100 = 60300 floats (16B-aligned planes)
  float* t1   = ws + 60304;         // 60000
  float* Rbuf = t1 + 60000;         // 180000
  dim3 b(256);
  int gp = (P_N  + 255) / 256;
  int gj = (NCOL + 255) / 256;
  int gm = P_N / ROWS;              // 1250

  // rhs = L(L(pnts)); new_pnts = (iA @ [rhs; crhs])[:P]
  mul_L_kernel<<<gp, b, 0, stream>>>(pnts, nbrs, wgts, diag, t1);
  mulL_pack_kernel<<<gj, b, 0, stream>>>(t1, nbrs, wgts, diag, crhs, rhsT);
  matvec_kernel<<<gm, b, 0, stream>>>(iA, rhsT, out);

  for (int it = 0; it < NUM_ITER; ++it) {
    compute_R_kernel<<<gp, b, 0, stream>>>(pnts, out, nbrs, wgts, Rbuf);
    dnew_kernel<<<gp, b, 0, stream>>>(pnts, nbrs, wgts, Rbuf, t1);
    mulL_pack_kernel<<<gj, b, 0, stream>>>(t1, nbrs, wgts, diag, crhs, rhsT);
    matvec_kernel<<<gm, b, 0, stream>>>(iA, rhsT, out);
  }
}

// Round 5
// 823.307 us; speedup vs baseline: 1.5049x; 1.5049x over previous
//
#include <hip/hip_runtime.h>

#define P_N   20000
#define K_N   16
#define C_N   100
#define NCOL  20100   // P + C
#define NC4   5025    // NCOL / 4 (exact)
#define NUM_ITER 2
#define ROWS  8       // rows per matvec block (divides P_N) -- R2-proven sweet spot
#define SB    64      // block size for per-vertex (latency-bound) kernels

typedef float f4 __attribute__((ext_vector_type(4)));

// ---------------- L-apply: out = sum_k x[nbr]*w + diag*x ----------------
__global__ __launch_bounds__(SB) void mul_L_kernel(const float* __restrict__ x,
    const int* __restrict__ nbrs, const float* __restrict__ wgts,
    const float* __restrict__ diag, float* __restrict__ out) {
  int p = blockIdx.x * blockDim.x + threadIdx.x;
  if (p >= P_N) return;
  float xx = x[3*p], xy = x[3*p+1], xz = x[3*p+2];
  float ax = 0.f, ay = 0.f, az = 0.f;
  #pragma unroll
  for (int k = 0; k < K_N; ++k) {
    int nb = nbrs[p*K_N + k];
    float w = wgts[p*K_N + k];
    ax += x[3*nb]   * w;
    ay += x[3*nb+1] * w;
    az += x[3*nb+2] * w;
  }
  float d = diag[p];
  out[3*p]   = ax + d*xx;
  out[3*p+1] = ay + d*xy;
  out[3*p+2] = az + d*xz;
}

// ------- fused: rhsT[:, j] = (L @ x)[j] for j<P, crhs for j>=P (3 planes) -------
__global__ __launch_bounds__(SB) void mulL_pack_kernel(const float* __restrict__ x,
    const int* __restrict__ nbrs, const float* __restrict__ wgts,
    const float* __restrict__ diag, const float* __restrict__ crhs,
    float* __restrict__ rhsT) {
  int j = blockIdx.x * blockDim.x + threadIdx.x;
  if (j >= NCOL) return;
  float v0, v1, v2;
  if (j < P_N) {
    float xx = x[3*j], xy = x[3*j+1], xz = x[3*j+2];
    float ax = 0.f, ay = 0.f, az = 0.f;
    #pragma unroll
    for (int k = 0; k < K_N; ++k) {
      int nb = nbrs[j*K_N + k];
      float w = wgts[j*K_N + k];
      ax += x[3*nb]   * w;
      ay += x[3*nb+1] * w;
      az += x[3*nb+2] * w;
    }
    float d = diag[j];
    v0 = ax + d*xx; v1 = ay + d*xy; v2 = az + d*xz;
  } else {
    int q = j - P_N;
    v0 = crhs[3*q]; v1 = crhs[3*q+1]; v2 = crhs[3*q+2];
  }
  rhsT[j] = v0; rhsT[NCOL + j] = v1; rhsT[2*NCOL + j] = v2;
}

// ------- GEMV, 8 rows per block, 3 rhs columns: out[row,:] = iA[row,:] @ rhsT -------
__global__ __launch_bounds__(256) void matvec_kernel(const float* __restrict__ A,
    const float* __restrict__ rhsT, float* __restrict__ out) {
  int row0 = blockIdx.x * ROWS;
  const f4* __restrict__ Ablk = reinterpret_cast<const f4*>(A) + (size_t)row0 * NC4;
  const f4* __restrict__ r0 = reinterpret_cast<const f4*>(rhsT);
  const f4* __restrict__ r1 = reinterpret_cast<const f4*>(rhsT + NCOL);
  const f4* __restrict__ r2 = reinterpret_cast<const f4*>(rhsT + 2*NCOL);
  float acc[ROWS][3];
  #pragma unroll
  for (int r = 0; r < ROWS; ++r) { acc[r][0] = 0.f; acc[r][1] = 0.f; acc[r][2] = 0.f; }
  for (int j = threadIdx.x; j < NC4; j += 256) {
    f4 b0 = r0[j];
    f4 b1 = r1[j];
    f4 b2 = r2[j];
    #pragma unroll
    for (int r = 0; r < ROWS; ++r) {
      f4 a = __builtin_nontemporal_load(Ablk + (size_t)r * NC4 + j);
      acc[r][0] = fmaf(a.x,b0.x, fmaf(a.y,b0.y, fmaf(a.z,b0.z, fmaf(a.w,b0.w, acc[r][0]))));
      acc[r][1] = fmaf(a.x,b1.x, fmaf(a.y,b1.y, fmaf(a.z,b1.z, fmaf(a.w,b1.w, acc[r][1]))));
      acc[r][2] = fmaf(a.x,b2.x, fmaf(a.y,b2.y, fmaf(a.z,b2.z, fmaf(a.w,b2.w, acc[r][2]))));
    }
  }
  // wave-level reduce
  #pragma unroll
  for (int off = 32; off > 0; off >>= 1) {
    #pragma unroll
    for (int r = 0; r < ROWS; ++r) {
      acc[r][0] += __shfl_down(acc[r][0], off);
      acc[r][1] += __shfl_down(acc[r][1], off);
      acc[r][2] += __shfl_down(acc[r][2], off);
    }
  }
  __shared__ float red[4][ROWS][3];
  int wid = threadIdx.x >> 6, lane = threadIdx.x & 63;
  if (lane == 0) {
    #pragma unroll
    for (int r = 0; r < ROWS; ++r) {
      red[wid][r][0] = acc[r][0];
      red[wid][r][1] = acc[r][1];
      red[wid][r][2] = acc[r][2];
    }
  }
  __syncthreads();
  if (threadIdx.x < ROWS*3) {
    int r = threadIdx.x / 3, c = threadIdx.x % 3;
    float s = red[0][r][c] + red[1][r][c] + red[2][r][c] + red[3][r][c];
    out[3*(row0+r)+c] = s;
  }
}

// ---------------- Jacobi rotation on symmetric S (pair PP<QQ, other RR), V accumulates ----------------
template<int PP, int QQ, int RR>
__device__ __forceinline__ void jacobi_rot(float S[3][3], float V[3][3]) {
  float apq = S[PP][QQ];
  if (fabsf(apq) < 1e-30f) return;
  float app = S[PP][PP], aqq = S[QQ][QQ];
  float tau = (aqq - app) / (2.0f * apq);
  float t = (tau >= 0.f ? 1.f : -1.f) / (fabsf(tau) + sqrtf(1.f + tau*tau));
  float c = 1.0f / sqrtf(1.f + t*t);
  float s = t * c;
  float arp = S[PP][RR], arq = S[QQ][RR];
  float npp = c*c*app - 2.f*s*c*apq + s*s*aqq;
  float nqq = s*s*app + 2.f*s*c*apq + c*c*aqq;
  S[PP][PP] = npp; S[QQ][QQ] = nqq;
  S[PP][QQ] = 0.f; S[QQ][PP] = 0.f;
  float narp = c*arp - s*arq;
  float narq = s*arp + c*arq;
  S[PP][RR] = narp; S[RR][PP] = narp;
  S[QQ][RR] = narq; S[RR][QQ] = narq;
  #pragma unroll
  for (int i = 0; i < 3; ++i) {
    float vp = V[i][PP], vq = V[i][QQ];
    V[i][PP] = c*vp - s*vq;
    V[i][QQ] = s*vp + c*vq;
  }
}

// ---------------- per-vertex Kabsch rotation from cov = N^T O ----------------
__global__ __launch_bounds__(SB) void compute_R_kernel(const float* __restrict__ oldp,
    const float* __restrict__ newp, const int* __restrict__ nbrs,
    const float* __restrict__ wgts, float* __restrict__ Rout) {
  int p = blockIdx.x * blockDim.x + threadIdx.x;
  if (p >= P_N) return;
  float ox = oldp[3*p], oy = oldp[3*p+1], oz = oldp[3*p+2];
  float nx = newp[3*p], ny = newp[3*p+1], nz = newp[3*p+2];
  float c00=0,c01=0,c02=0,c10=0,c11=0,c12=0,c20=0,c21=0,c22=0;
  #pragma unroll
  for (int k = 0; k < K_N; ++k) {
    int nb = nbrs[p*K_N + k];
    float w = wgts[p*K_N + k];
    float Ox = (ox - oldp[3*nb])   * w;
    float Oy = (oy - oldp[3*nb+1]) * w;
    float Oz = (oz - oldp[3*nb+2]) * w;
    float Nx = (nx - newp[3*nb])   * w;
    float Ny = (ny - newp[3*nb+1]) * w;
    float Nz = (nz - newp[3*nb+2]) * w;
    c00 += Nx*Ox; c01 += Nx*Oy; c02 += Nx*Oz;
    c10 += Ny*Ox; c11 += Ny*Oy; c12 += Ny*Oz;
    c20 += Nz*Ox; c21 += Nz*Oy; c22 += Nz*Oz;
  }
  float S[3][3];
  S[0][0] = c00*c00 + c10*c10 + c20*c20;
  S[1][1] = c01*c01 + c11*c11 + c21*c21;
  S[2][2] = c02*c02 + c12*c12 + c22*c22;
  S[0][1] = c00*c01 + c10*c11 + c20*c21; S[1][0] = S[0][1];
  S[0][2] = c00*c02 + c10*c12 + c20*c22; S[2][0] = S[0][2];
  S[1][2] = c01*c02 + c11*c12 + c21*c22; S[2][1] = S[1][2];
  float V[3][3] = {{1.f,0.f,0.f},{0.f,1.f,0.f},{0.f,0.f,1.f}};
  #pragma unroll
  for (int sweep = 0; sweep < 8; ++sweep) {
    jacobi_rot<0,1,2>(S, V);
    jacobi_rot<0,2,1>(S, V);
    jacobi_rot<1,2,0>(S, V);
  }
  float e0 = S[0][0], e1 = S[1][1], e2 = S[2][2];
  float v0x=V[0][0], v0y=V[1][0], v0z=V[2][0];
  float v1x=V[0][1], v1y=V[1][1], v1z=V[2][1];
  float v2x=V[0][2], v2y=V[1][2], v2z=V[2][2];
  float te, tx, ty, tz;
  if (e1 > e0) { te=e0;e0=e1;e1=te; tx=v0x;ty=v0y;tz=v0z; v0x=v1x;v0y=v1y;v0z=v1z; v1x=tx;v1y=ty;v1z=tz; }
  if (e2 > e0) { te=e0;e0=e2;e2=te; tx=v0x;ty=v0y;tz=v0z; v0x=v2x;v0y=v2y;v0z=v2z; v2x=tx;v2y=ty;v2z=tz; }
  if (e2 > e1) { te=e1;e1=e2;e2=te; tx=v1x;ty=v1y;tz=v1z; v1x=v2x;v1y=v2y;v1z=v2z; v2x=tx;v2y=ty;v2z=tz; }
  float u0x = c00*v0x + c01*v0y + c02*v0z;
  float u0y = c10*v0x + c11*v0y + c12*v0z;
  float u0z = c20*v0x + c21*v0y + c22*v0z;
  float n0 = sqrtf(u0x*u0x + u0y*u0y + u0z*u0z);
  float R00,R01,R02,R10,R11,R12,R20,R21,R22;
  if (n0 < 1e-25f) {
    R00=1.f;R01=0.f;R02=0.f;R10=0.f;R11=1.f;R12=0.f;R20=0.f;R21=0.f;R22=1.f;
  } else {
    float in0 = 1.f/n0; u0x*=in0; u0y*=in0; u0z*=in0;
    float u1x = c00*v1x + c01*v1y + c02*v1z;
    float u1y = c10*v1x + c11*v1y + c12*v1z;
    float u1z = c20*v1x + c21*v1y + c22*v1z;
    float d01 = u1x*u0x + u1y*u0y + u1z*u0z;
    u1x -= d01*u0x; u1y -= d01*u0y; u1z -= d01*u0z;
    float n1 = sqrtf(u1x*u1x + u1y*u1y + u1z*u1z);
    if (n1 > 1e-6f * n0) {
      float in1 = 1.f/n1; u1x*=in1; u1y*=in1; u1z*=in1;
    } else {
      if (fabsf(u0x) < 0.7f) {
        float nn = 1.f/sqrtf(u0z*u0z + u0y*u0y + 1e-30f);
        u1x = 0.f; u1y = u0z*nn; u1z = -u0y*nn;
      } else {
        float nn = 1.f/sqrtf(u0z*u0z + u0x*u0x + 1e-30f);
        u1x = -u0z*nn; u1y = 0.f; u1z = u0x*nn;
      }
    }
    float u2x = u0y*u1z - u0z*u1y;
    float u2y = u0z*u1x - u0x*u1z;
    float u2z = u0x*u1y - u0y*u1x;
    float detV = v0x*(v1y*v2z - v1z*v2y) - v0y*(v1x*v2z - v1z*v2x) + v0z*(v1x*v2y - v1y*v2x);
    float sg = (detV >= 0.f) ? 1.f : -1.f;
    R00 = u0x*v0x + u1x*v1x + sg*u2x*v2x;
    R01 = u0x*v0y + u1x*v1y + sg*u2x*v2y;
    R02 = u0x*v0z + u1x*v1z + sg*u2x*v2z;
    R10 = u0y*v0x + u1y*v1x + sg*u2y*v2x;
    R11 = u0y*v0y + u1y*v1y + sg*u2y*v2y;
    R12 = u0y*v0z + u1y*v1z + sg*u2y*v2z;
    R20 = u0z*v0x + u1z*v1x + sg*u2z*v2x;
    R21 = u0z*v0y + u1z*v1y + sg*u2z*v2y;
    R22 = u0z*v0z + u1z*v1z + sg*u2z*v2z;
  }
  float* Rp = Rout + (size_t)p * 9;
  Rp[0]=R00; Rp[1]=R01; Rp[2]=R02;
  Rp[3]=R10; Rp[4]=R11; Rp[5]=R12;
  Rp[6]=R20; Rp[7]=R21; Rp[8]=R22;
}

// ---------------- d_new = sum_k 0.5*w_k*(R[nbr]+R[p]) @ O_k ----------------
__global__ __launch_bounds__(SB) void dnew_kernel(const float* __restrict__ oldp,
    const int* __restrict__ nbrs, const float* __restrict__ wgts,
    const float* __restrict__ Rbuf, float* __restrict__ dnew) {
  int p = blockIdx.x * blockDim.x + threadIdx.x;
  if (p >= P_N) return;
  float ox = oldp[3*p], oy = oldp[3*p+1], oz = oldp[3*p+2];
  const float* Rp = Rbuf + (size_t)p * 9;
  float p00=Rp[0],p01=Rp[1],p02=Rp[2],p10=Rp[3],p11=Rp[4],p12=Rp[5],p20=Rp[6],p21=Rp[7],p22=Rp[8];
  float ax = 0.f, ay = 0.f, az = 0.f;
  #pragma unroll
  for (int k = 0; k < K_N; ++k) {
    int nb = nbrs[p*K_N + k];
    float w = wgts[p*K_N + k];
    float Ox = (ox - oldp[3*nb])   * w;
    float Oy = (oy - oldp[3*nb+1]) * w;
    float Oz = (oz - oldp[3*nb+2]) * w;
    const float* Rn = Rbuf + (size_t)nb * 9;
    float r00=Rn[0]+p00, r01=Rn[1]+p01, r02=Rn[2]+p02;
    float r10=Rn[3]+p10, r11=Rn[4]+p11, r12=Rn[5]+p12;
    float r20=Rn[6]+p20, r21=Rn[7]+p21, r22=Rn[8]+p22;
    float hw = 0.5f * w;
    ax += hw * (r00*Ox + r01*Oy + r02*Oz);
    ay += hw * (r10*Ox + r11*Oy + r12*Oz);
    az += hw * (r20*Ox + r21*Oy + r22*Oz);
  }
  dnew[3*p]   = ax;
  dnew[3*p+1] = ay;
  dnew[3*p+2] = az;
}

extern "C" void kernel_launch(void* const* d_in, const int* in_sizes, int n_in,
                              void* d_out, int out_size, void* d_ws, size_t ws_size,
                              hipStream_t stream) {
  const float* pnts = (const float*)d_in[0];
  const int*   nbrs = (const int*)d_in[1];
  const float* wgts = (const float*)d_in[2];
  const float* diag = (const float*)d_in[3];
  const float* crhs = (const float*)d_in[4];
  const float* iA   = (const float*)d_in[5];
  float* out = (float*)d_out;

  float* ws   = (float*)d_ws;
  float* rhsT = ws;                 // 3 * 20100 = 60300 floats (16B-aligned planes)
  float* t1   = ws + 60304;         // 60000
  float* Rbuf = t1 + 60000;         // 180000
  dim3 bs(SB), bm(256);
  int gp = (P_N  + SB - 1) / SB;    // 313
  int gj = (NCOL + SB - 1) / SB;    // 315
  int gm = P_N / ROWS;              // 2500

  // rhs = L(L(pnts)); new_pnts = (iA @ [rhs; crhs])[:P]
  mul_L_kernel<<<gp, bs, 0, stream>>>(pnts, nbrs, wgts, diag, t1);
  mulL_pack_kernel<<<gj, bs, 0, stream>>>(t1, nbrs, wgts, diag, crhs, rhsT);
  matvec_kernel<<<gm, bm, 0, stream>>>(iA, rhsT, out);

  for (int it = 0; it < NUM_ITER; ++it) {
    compute_R_kernel<<<gp, bs, 0, stream>>>(pnts, out, nbrs, wgts, Rbuf);
    dnew_kernel<<<gp, bs, 0, stream>>>(pnts, nbrs, wgts, Rbuf, t1);
    mulL_pack_kernel<<<gj, bs, 0, stream>>>(t1, nbrs, wgts, diag, crhs, rhsT);
    matvec_kernel<<<gm, bm, 0, stream>>>(iA, rhsT, out);
  }
}